// Round 7
// baseline (24544.841 us; speedup 1.0000x reference)
//
#include <hip/hip_runtime.h>
#include <stdint.h>

// ---------------------------------------------------------------------------
// Seq2seq LSTM autoencoder (T=4096, H=1024, L=2), fp32 end-to-end.
// Round 10: round-9 protocol (tagged u64 single-hop exchange, coalesced
// wave-0 publish) with the post-gate path deserialized:
//   - barrier #2 removed. Lane 0 of wave w writes gh[w] then RELEASE-bumps
//     an LDS counter; wave 0 ACQUIRE-spins for 8 bumps and publishes
//     immediately (8 adjacent lanes -> one 64B line, as round 9). Waves
//     1..7 go straight to the next step's poll -> publish latency overlaps
//     discovery instead of following a full barrier.
//   - double-buffered LDS stage -> exactly ONE __syncthreads per step
//     (fill buf[(t+1)&1] while laggards still dot buf[t&1]; gh is safe
//     single-buffered: wave 0 reaches barrier(t+1) only after its publish
//     reads of step t, and gh writes for t+1 happen only after barrier(t+1)).
//   - poll pacing: first 8 iterations sleep-free, then s_sleep(1) (was
//     s_sleep(4) every iteration) -> smaller discovery quantum; IC poll
//     bandwidth has headroom (round-7 evidence).
// Unchanged: stream layout/tags/magics, FP summation order (absmax 6.1e-5),
// wave-per-row compute, 128 blocks x 512 thr per layer (1 block/CU), tiled
// proj_out, panic escape, memset re-poison.
// Schedule: pair(enc L0, enc L1) -> pair(dec L0, dec L1) -> proj.
// Deadlock-free: layer-A never waits on layer-B; intra-block handshake is
// acyclic (all lane0s bump unconditionally; wave0 alone publishes).
// ---------------------------------------------------------------------------

#define T_STEPS 4096
#define H_DIM   1024
#define SLOT_U64 1024             // 1024 elements x (2 tagged dwords = 1 u64)
#define SLOT_DW  2048
#define NSLOT   4097
#define M1 0x7E57u
#define M2 0x7E58u
#define PANIC_ITERS (1u<<25)

using u32 = uint32_t;
using u64 = unsigned long long;

static __device__ __forceinline__ float sigf(float x){ return 1.0f/(1.0f+__expf(-x)); }
static __device__ __forceinline__ float tanh_f(float x){
  x = fminf(20.f, fmaxf(-20.f, x));
  float e = __expf(-2.f*x);
  return (1.f-e)/(1.f+e);
}

static __device__ __forceinline__ bool tag_ok(u64 v, u32 magic){
  return ((((u32)(v>>16))&0xFFFFu)==magic) & (((u32)(v>>48))==magic);
}
static __device__ __forceinline__ float untag1(u64 v){
  return __uint_as_float( (((u32)v)&0xFFFFu) | (((u32)(v>>32))<<16) );
}
static __device__ __forceinline__ u64 tag1(u32 magic, float h){
  u32 b=__float_as_uint(h);
  u64 lo = (u64)((magic<<16)|(b&0xFFFFu));
  u64 hi = ((u64)((magic<<16)|(b>>16)))<<32;
  return hi|lo;
}

// Poll 2 tagged elements (one u64 each) until valid; deposit into LDS.
// First 8 iterations sleep-free, then s_sleep(1); panic escape preserved.
static __device__ __forceinline__ void poll_h2(const u64* __restrict__ q,
                                               u32 magic, float* dst,
                                               u32* panic){
  u64 v0=0,v1=0; bool ok0=false,ok1=false; u32 it=0;
  for(;;){
    if(!ok0) v0=__hip_atomic_load(q,  __ATOMIC_RELAXED,__HIP_MEMORY_SCOPE_AGENT);
    if(!ok1) v1=__hip_atomic_load(q+1,__ATOMIC_RELAXED,__HIP_MEMORY_SCOPE_AGENT);
    ok0 = ok0 || tag_ok(v0,magic);
    ok1 = ok1 || tag_ok(v1,magic);
    if(ok0 & ok1) break;
    ++it;
    if(it>8u) __builtin_amdgcn_s_sleep(1);
    if((it & 1023u)==0u){
      if(__hip_atomic_load(panic,__ATOMIC_RELAXED,__HIP_MEMORY_SCOPE_AGENT)==0xDEADBEEFu) break;
      if(it>PANIC_ITERS){ __hip_atomic_store(panic,0xDEADBEEFu,__ATOMIC_RELAXED,__HIP_MEMORY_SCOPE_AGENT); break; }
    }
  }
  dst[0]=untag1(v0);
  dst[1]=untag1(v1);
}

// Poll 2 IN + 2 H tagged elements concurrently (modes 1/3).
static __device__ __forceinline__ void poll_in2h2(const u64* __restrict__ qa, u32 mA,
                                                  const u64* __restrict__ qb, u32 mB,
                                                  float* da, float* db, u32* panic){
  u64 a0=0,a1=0,b0=0,b1=0; bool oa0=false,oa1=false,ob0=false,ob1=false; u32 it=0;
  for(;;){
    if(!oa0) a0=__hip_atomic_load(qa,  __ATOMIC_RELAXED,__HIP_MEMORY_SCOPE_AGENT);
    if(!oa1) a1=__hip_atomic_load(qa+1,__ATOMIC_RELAXED,__HIP_MEMORY_SCOPE_AGENT);
    if(!ob0) b0=__hip_atomic_load(qb,  __ATOMIC_RELAXED,__HIP_MEMORY_SCOPE_AGENT);
    if(!ob1) b1=__hip_atomic_load(qb+1,__ATOMIC_RELAXED,__HIP_MEMORY_SCOPE_AGENT);
    oa0 = oa0 || tag_ok(a0,mA);
    oa1 = oa1 || tag_ok(a1,mA);
    ob0 = ob0 || tag_ok(b0,mB);
    ob1 = ob1 || tag_ok(b1,mB);
    if(oa0 & oa1 & ob0 & ob1) break;
    ++it;
    if(it>8u) __builtin_amdgcn_s_sleep(1);
    if((it & 1023u)==0u){
      if(__hip_atomic_load(panic,__ATOMIC_RELAXED,__HIP_MEMORY_SCOPE_AGENT)==0xDEADBEEFu) break;
      if(it>PANIC_ITERS){ __hip_atomic_store(panic,0xDEADBEEFu,__ATOMIC_RELAXED,__HIP_MEMORY_SCOPE_AGENT); break; }
    }
  }
  da[0]=untag1(a0); da[1]=untag1(a1);
  db[0]=untag1(b0); db[1]=untag1(b1);
}

// Stage step ts into buffer S (poll = single-hop tagged exchange).
static __device__ __forceinline__ void stage_step(
    int ts, float* S, int mode, int e0, int fb, int fbH,
    const float* __restrict__ xin, const u64* __restrict__ instream,
    const u64* __restrict__ own, u32 m_in, u32 m_own, u32* panic)
{
  if(mode==0){
    float2 xv=*(const float2*)(xin + (size_t)ts*H_DIM + e0);   // issue early
    poll_h2(own + (size_t)ts*SLOT_U64 + e0, m_own, S+fbH, panic);
    S[fb]=xv.x; S[fb+1]=xv.y;                                  // lands in poll
  } else if(mode==2){
    poll_h2(own + (size_t)ts*SLOT_U64 + e0, m_own, S+fbH, panic);
  } else {
    poll_in2h2(instream + (size_t)(ts+1)*SLOT_U64 + e0, m_in,
               own      + (size_t)ts*SLOT_U64     + e0, m_own,
               S+fb, S+fbH, panic);
  }
}

// One LSTM layer over T steps. kb = block index within the layer (0..127).
// Block owns h-rows hr0..hr0+7; wave w owns row r=hr0+w entirely (4 gates).
// Lane l = one 32-col segment (lanes 0-31 input part, 32-63 h part).
// Thread stages stream elements 2*tid, 2*tid+1 of both IN and H parts.
// mode 0: input = raw x.  mode 1/3: input = tagged stream (m_in).
// mode 2: input = CONSTANT tagged slot (staged once into both buffers).
static __device__ __forceinline__ void lstm_scan_body(
    int kb, int tid, float (*st)[2304], float* gh, u32* ghc,
    const float* __restrict__ xin,
    const u64*  __restrict__ instream,
    u64*        __restrict__ own,
    u32 m_in, u32 m_own,
    const float* __restrict__ Wih, const float* __restrict__ Whh,
    const float* __restrict__ bih, const float* __restrict__ bhh,
    const float* __restrict__ c0,      // null -> zeros
    float*       __restrict__ cout,    // final c per row
    const u64*  __restrict__ h0slot,   // tagged slot holding h0; null -> zeros
    float*       __restrict__ fh_out,  // if non-null: write final h (enc L1)
    u32* __restrict__ panic,
    int mode)
{
  const int hr0=kb*8;
  const int w=tid>>6, l=tid&63;
  const int r = hr0 + w;                   // this wave's h row
  const int e0 = 2*tid;                    // first owned stream element
  const int fb  = e0 + 4*(e0>>5);          // stage word, IN part (2 elems)
  const int fbH = 1152+fb;                 // stage word, H part
  const int sb  = l*36;                    // dot segment word base

  // fp32 weights in registers: 4 gate rows (i,f,g,o) x 32-col segment
  float wr0[32],wr1[32],wr2[32],wr3[32];
  {
    const size_t GS = (size_t)1024*1024;   // gate stride in floats
    const float* srcb = (l<32) ? Wih + (size_t)r*H_DIM + l*32
                               : Whh + (size_t)r*H_DIM + (l-32)*32;
    #pragma unroll
    for(int i=0;i<8;i++){
      float4 a0=*(const float4*)(srcb + i*4);
      float4 a1=*(const float4*)(srcb + GS + i*4);
      float4 a2=*(const float4*)(srcb + 2*GS + i*4);
      float4 a3=*(const float4*)(srcb + 3*GS + i*4);
      wr0[4*i]=a0.x; wr0[4*i+1]=a0.y; wr0[4*i+2]=a0.z; wr0[4*i+3]=a0.w;
      wr1[4*i]=a1.x; wr1[4*i+1]=a1.y; wr1[4*i+2]=a1.z; wr1[4*i+3]=a1.w;
      wr2[4*i]=a2.x; wr2[4*i+1]=a2.y; wr2[4*i+2]=a2.z; wr2[4*i+3]=a2.w;
      wr3[4*i]=a3.x; wr3[4*i+1]=a3.y; wr3[4*i+2]=a3.z; wr3[4*i+3]=a3.w;
    }
  }

  if(tid==0) *ghc=0u;

  float bI=0,bF=0,bG=0,bO=0,c_st=0.f,h_st=0.f;   // valid on lane 0 of each wave
  if(l==0){
    bI=bih[r]       + bhh[r];
    bF=bih[r+1024]  + bhh[r+1024];
    bG=bih[r+2048]  + bhh[r+2048];
    bO=bih[r+3072]  + bhh[r+3072];
    if(c0)     c_st=c0[r];
    if(h0slot) h_st=untag1(h0slot[r]);
  }
  __syncthreads();                         // ghc=0 visible before first bump
  if(l==0){
    gh[w]=h_st;
    __hip_atomic_fetch_add(ghc,1u,__ATOMIC_RELEASE,__HIP_MEMORY_SCOPE_WORKGROUP);
  }
  if(mode==2){                 // constant input: stage once into BOTH buffers
    float v0=untag1(instream[e0]), v1=untag1(instream[e0+1]);
    st[0][fb]=v0; st[0][fb+1]=v1;
    st[1][fb]=v0; st[1][fb+1]=v1;
  }
  // wave 0: wait for the 8 h0 values, publish slot 0 (one 64B transaction)
  if(w==0){
    u32 it=0;
    while(__hip_atomic_load(ghc,__ATOMIC_ACQUIRE,__HIP_MEMORY_SCOPE_WORKGROUP) < 8u){
      if(((++it)&4095u)==0u){
        if(__hip_atomic_load(panic,__ATOMIC_RELAXED,__HIP_MEMORY_SCOPE_AGENT)==0xDEADBEEFu) break;
        if(it>PANIC_ITERS){ __hip_atomic_store(panic,0xDEADBEEFu,__ATOMIC_RELAXED,__HIP_MEMORY_SCOPE_AGENT); break; }
      }
    }
    if(l<8){
      float hv=__hip_atomic_load(gh+l,__ATOMIC_RELAXED,__HIP_MEMORY_SCOPE_WORKGROUP);
      __hip_atomic_store(own + hr0 + l, tag1(m_own, hv),
                         __ATOMIC_RELAXED,__HIP_MEMORY_SCOPE_AGENT);
    }
  }
  // stage step 0 into buffer 0 (all waves; spins until publishes land)
  stage_step(0, st[0], mode, e0, fb, fbH, xin, instream, own, m_in, m_own, panic);

  for(int t=0;t<T_STEPS;++t){
    __syncthreads();                       // buf[t&1] fully staged
    float* S = st[t&1];
    // --- dot: 4 gates of row r over this lane's 32-col segment ---
    float p0=0.f,p1=0.f,p2=0.f,p3=0.f;
    #pragma unroll
    for(int i=0;i<8;i++){
      float4 s=*(const float4*)(S+sb+i*4);
      p0+=s.x*wr0[4*i]+s.y*wr0[4*i+1]+s.z*wr0[4*i+2]+s.w*wr0[4*i+3];
      p1+=s.x*wr1[4*i]+s.y*wr1[4*i+1]+s.z*wr1[4*i+2]+s.w*wr1[4*i+3];
      p2+=s.x*wr2[4*i]+s.y*wr2[4*i+1]+s.z*wr2[4*i+2]+s.w*wr2[4*i+3];
      p3+=s.x*wr3[4*i]+s.y*wr3[4*i+1]+s.z*wr3[4*i+2]+s.w*wr3[4*i+3];
    }
    #pragma unroll
    for(int off=32;off;off>>=1){
      p0+=__shfl_down(p0,off,64); p1+=__shfl_down(p1,off,64);
      p2+=__shfl_down(p2,off,64); p3+=__shfl_down(p3,off,64);
    }
    // --- gates in-wave (lane 0); gh + counter bump (release) ---
    if(l==0){
      float gi=bI+p0, gf=bF+p1, gg=bG+p2, go=bO+p3;
      c_st = sigf(gf)*c_st + sigf(gi)*tanh_f(gg);
      h_st = sigf(go)*tanh_f(c_st);
      gh[w]=h_st;
      __hip_atomic_fetch_add(ghc,1u,__ATOMIC_RELEASE,__HIP_MEMORY_SCOPE_WORKGROUP);
      if(t==T_STEPS-1){
        cout[r]=c_st;
        if(fh_out) fh_out[r]=h_st;
      }
    }
    // --- wave 0: handshake + coalesced publish of slot t+1 ---
    if(w==0){
      const u32 want = 8u*((u32)t+2u);
      u32 it=0;
      while(__hip_atomic_load(ghc,__ATOMIC_ACQUIRE,__HIP_MEMORY_SCOPE_WORKGROUP) < want){
        if(((++it)&4095u)==0u){
          if(__hip_atomic_load(panic,__ATOMIC_RELAXED,__HIP_MEMORY_SCOPE_AGENT)==0xDEADBEEFu) break;
          if(it>PANIC_ITERS){ __hip_atomic_store(panic,0xDEADBEEFu,__ATOMIC_RELAXED,__HIP_MEMORY_SCOPE_AGENT); break; }
        }
      }
      if(l<8){
        float hv=__hip_atomic_load(gh+l,__ATOMIC_RELAXED,__HIP_MEMORY_SCOPE_WORKGROUP);
        __hip_atomic_store(own + (size_t)(t+1)*SLOT_U64 + hr0 + l,
                           tag1(m_own, hv),
                           __ATOMIC_RELAXED,__HIP_MEMORY_SCOPE_AGENT);
      }
    }
    // --- stage step t+1 into the other buffer (no barrier needed:
    //     laggards read buf[t&1], we write buf[(t+1)&1]) ---
    if(t<T_STEPS-1){
      stage_step(t+1, st[(t+1)&1], mode, e0, fb, fbH,
                 xin, instream, own, m_in, m_own, panic);
    }
    // gh single-buffer safety: gh writes for step t+1 happen only after
    // barrier(t+1), which wave 0 reaches only after its publish reads of t.
  }
}

// Fused layer pair: blocks [0,128) = layer A, [128,256) = layer B.
// B consumes A's stream with 1-step skew. A never waits on B.
__global__ __launch_bounds__(512,2) void lstm_scan_pair(
    const float* __restrict__ xinA,
    const u64*  __restrict__ insA, u64* __restrict__ ownA, u32 miA, u32 moA,
    const float* __restrict__ WihA, const float* __restrict__ WhhA,
    const float* __restrict__ bihA, const float* __restrict__ bhhA,
    const float* __restrict__ c0A, float* __restrict__ coutA,
    const u64*  __restrict__ h0A, float* __restrict__ fhA, int modeA,
    const u64*  __restrict__ insB, u64* __restrict__ ownB, u32 miB, u32 moB,
    const float* __restrict__ WihB, const float* __restrict__ WhhB,
    const float* __restrict__ bihB, const float* __restrict__ bhhB,
    const float* __restrict__ c0B, float* __restrict__ coutB,
    const u64*  __restrict__ h0B, float* __restrict__ fhB, int modeB,
    u32* __restrict__ panic)
{
  __shared__ __align__(16) float st[2][2304];
  __shared__ float gh[8];
  __shared__ u32 ghc;
  const int b=blockIdx.x, tid=threadIdx.x;
  if(b<128){
    lstm_scan_body(b, tid, st, gh, &ghc, xinA, insA, ownA, miA, moA,
                   WihA, WhhA, bihA, bhhA, c0A, coutA, h0A, fhA, panic, modeA);
  } else {
    lstm_scan_body(b-128, tid, st, gh, &ghc, nullptr, insB, ownB, miB, moB,
                   WihB, WhhB, bihB, bhhB, c0B, coutB, h0B, fhB, panic, modeB);
  }
}

// out[(4095-tp), o] = leaky( sum_k oW[o,k] * h1d[tp][k] + ob[o] )
// Tiled: each block handles PTILE timesteps, staging h in LDS, so out_W is
// read 256x total (1 GB LLC traffic) instead of 4096x (16 GB).
#define PTILE 16
__global__ __launch_bounds__(256,2) void proj_out(
    const u64* __restrict__ SB, const float* __restrict__ oW,
    const float* __restrict__ ob, float* __restrict__ out)
{
  __shared__ __align__(16) float hb[PTILE][1024];
  const int tp0=blockIdx.x*PTILE, tid=threadIdx.x;
  for(int i=0;i<PTILE;i++){
    u64 v0=SB[(size_t)(tp0+i+1)*SLOT_U64 + tid*4 + 0];
    u64 v1=SB[(size_t)(tp0+i+1)*SLOT_U64 + tid*4 + 1];
    u64 v2=SB[(size_t)(tp0+i+1)*SLOT_U64 + tid*4 + 2];
    u64 v3=SB[(size_t)(tp0+i+1)*SLOT_U64 + tid*4 + 3];
    float4 f; f.x=untag1(v0); f.y=untag1(v1); f.z=untag1(v2); f.w=untag1(v3);
    *(float4*)&hb[i][tid*4]=f;
  }
  __syncthreads();
  #pragma unroll
  for(int j=0;j<4;j++){
    int o = tid + 256*j;
    const float* wr = oW + (size_t)o*H_DIM;
    float acc[PTILE];
    #pragma unroll
    for(int i=0;i<PTILE;i++) acc[i]=0.f;
    for(int k=0;k<1024;k+=4){
      float4 wv=*(const float4*)(wr+k);
      #pragma unroll
      for(int i=0;i<PTILE;i++){
        acc[i] += wv.x*hb[i][k]+wv.y*hb[i][k+1]+wv.z*hb[i][k+2]+wv.w*hb[i][k+3];
      }
    }
    float bo=ob[o];
    #pragma unroll
    for(int i=0;i<PTILE;i++){
      float a=acc[i]+bo;
      a = a>0.f ? a : 0.01f*a;
      out[(size_t)(4095-(tp0+i))*H_DIM + o]=a;
    }
  }
}

extern "C" void kernel_launch(void* const* d_in, const int* in_sizes, int n_in,
                              void* d_out, int out_size, void* d_ws, size_t ws_size,
                              hipStream_t stream) {
  const float* x    = (const float*)d_in[0];
  const float* eWih = (const float*)d_in[1];
  const float* eWhh = (const float*)d_in[2];
  const float* ebih = (const float*)d_in[3];
  const float* ebhh = (const float*)d_in[4];
  const float* dWih = (const float*)d_in[5];
  const float* dWhh = (const float*)d_in[6];
  const float* dbih = (const float*)d_in[7];
  const float* dbhh = (const float*)d_in[8];
  const float* oW   = (const float*)d_in[9];
  const float* ob   = (const float*)d_in[10];
  float* out = (float*)d_out;
  u32* ws = (u32*)d_ws;

  const size_t REGION = (size_t)NSLOT*SLOT_DW;     // in dwords
  u64*   SA    = (u64*)ws;
  u64*   SB    = (u64*)(ws + REGION);
  float* CA    = (float*)(ws + 2*REGION);          // 2048 floats: enc c finals
  u32*   panic = ws + 2*REGION + 2048;
  const size_t LSTRIDE = (size_t)4096*1024;        // per-layer weight stride

  // clear tags + c buffer + panic (stale same-magic tags from the previous
  // graph iteration must never false-positive)
  size_t clr_bytes = (2*REGION + 2048 + 64)*4;
  hipMemsetAsync(d_ws, 0, clr_bytes, stream);

  // Phase 1: enc L0 (mode 0, x -> SA/M1, zero init) || enc L1 (mode 1,
  // SA/M1 -> SB/M1, zero init, writes final_hidden to out tail).
  lstm_scan_pair<<<256,512,0,stream>>>(
      x, nullptr, SA, 0u, M1,
      eWih, eWhh, ebih, ebhh,
      nullptr, CA, nullptr, nullptr, 0,
      SA, SB, M1, M1,
      eWih+LSTRIDE, eWhh+LSTRIDE, ebih+4096, ebhh+4096,
      nullptr, CA+1024, nullptr, out + (size_t)T_STEPS*H_DIM, 1,
      panic);

  // Phase 2: dec L0 (mode 2, const input = final_hidden = SB slot 4096,
  // stream SA reused with M2, init h=SA slot 4096 / c=CA) || dec L1
  // (mode 3, SA/M2 -> SB/M2, init h=SB slot 4096 / c=CA+1024).
  lstm_scan_pair<<<256,512,0,stream>>>(
      nullptr, SB + (size_t)4096*SLOT_U64, SA, 0u, M2,
      dWih, dWhh, dbih, dbhh,
      CA, CA, SA + (size_t)4096*SLOT_U64, nullptr, 2,
      SA, SB, M2, M2,
      dWih+LSTRIDE, dWhh+LSTRIDE, dbih+4096, dbhh+4096,
      CA+1024, CA+1024, SB + (size_t)4096*SLOT_U64, nullptr, 3,
      panic);

  // projection + leaky ReLU + flip
  proj_out<<<256,256,0,stream>>>(SB, oW, ob, out);
}

// Round 8
// 22826.613 us; speedup vs baseline: 1.0753x; 1.0753x over previous
//
#include <hip/hip_runtime.h>
#include <stdint.h>

// ---------------------------------------------------------------------------
// Seq2seq LSTM autoencoder (T=4096, H=1024, L=2), fp32 end-to-end.
// Round 11: round-9 structure EXACTLY (23.0 ms proven; round 10's handshake
// + double-buffer bundle regressed because waves 1-7's polls contended with
// wave 0's publish store). Two isolated micro-changes only:
//   1) poll pacing s_sleep(4) -> s_sleep(1): poll period ~0.41 -> ~0.33us,
//      shrinking discovery mean + the quantization tail maxed by barrier #1.
//   2) s_setprio(1) around wave 0's publish store: after barrier #2 the
//      publish competes with 7 waves' freshly-issued polls for memory-issue
//      slots; priority gets the critical store out first (round-10 lesson).
// Everything else identical to round 9: tagged u64 single-hop exchange
// (data IS readiness; one IC round trip), coalesced 8-lane wave-0 publish
// (one 64B line), wave-per-row compute with in-wave shfl reduce, single
// LDS stage buffer with 2 barriers/step, 128 blocks x 512 thr per layer
// (1 block/CU), tiled proj_out, panic escape, memset re-poison.
// Schedule: pair(enc L0, enc L1) -> pair(dec L0, dec L1) -> proj.
// Deadlock-free: layer-A blocks never wait on layer-B.
// ---------------------------------------------------------------------------

#define T_STEPS 4096
#define H_DIM   1024
#define SLOT_U64 1024             // 1024 elements x (2 tagged dwords = 1 u64)
#define SLOT_DW  2048
#define NSLOT   4097
#define M1 0x7E57u
#define M2 0x7E58u
#define PANIC_ITERS (1u<<25)

using u32 = uint32_t;
using u64 = unsigned long long;

static __device__ __forceinline__ float sigf(float x){ return 1.0f/(1.0f+__expf(-x)); }
static __device__ __forceinline__ float tanh_f(float x){
  x = fminf(20.f, fmaxf(-20.f, x));
  float e = __expf(-2.f*x);
  return (1.f-e)/(1.f+e);
}

static __device__ __forceinline__ bool tag_ok(u64 v, u32 magic){
  return ((((u32)(v>>16))&0xFFFFu)==magic) & (((u32)(v>>48))==magic);
}
static __device__ __forceinline__ float untag1(u64 v){
  return __uint_as_float( (((u32)v)&0xFFFFu) | (((u32)(v>>32))<<16) );
}
static __device__ __forceinline__ u64 tag1(u32 magic, float h){
  u32 b=__float_as_uint(h);
  u64 lo = (u64)((magic<<16)|(b&0xFFFFu));
  u64 hi = ((u64)((magic<<16)|(b>>16)))<<32;
  return hi|lo;
}

// Poll 2 tagged elements (one u64 each) until valid; deposit into LDS.
// s_sleep(1)-paced (round-11 change); panic escape for true deadlocks.
static __device__ __forceinline__ void poll_h2(const u64* __restrict__ q,
                                               u32 magic, float* dst,
                                               u32* panic){
  u64 v0=0,v1=0; bool ok0=false,ok1=false; u32 it=0;
  for(;;){
    if(!ok0) v0=__hip_atomic_load(q,  __ATOMIC_RELAXED,__HIP_MEMORY_SCOPE_AGENT);
    if(!ok1) v1=__hip_atomic_load(q+1,__ATOMIC_RELAXED,__HIP_MEMORY_SCOPE_AGENT);
    ok0 = ok0 || tag_ok(v0,magic);
    ok1 = ok1 || tag_ok(v1,magic);
    if(ok0 & ok1) break;
    ++it;
    if((it & 255u)==0u){
      if(__hip_atomic_load(panic,__ATOMIC_RELAXED,__HIP_MEMORY_SCOPE_AGENT)==0xDEADBEEFu) break;
      if(it>PANIC_ITERS){ __hip_atomic_store(panic,0xDEADBEEFu,__ATOMIC_RELAXED,__HIP_MEMORY_SCOPE_AGENT); break; }
    }
    __builtin_amdgcn_s_sleep(1);
  }
  dst[0]=untag1(v0);
  dst[1]=untag1(v1);
}

// Poll 2 IN + 2 H tagged elements concurrently (modes 1/3).
static __device__ __forceinline__ void poll_in2h2(const u64* __restrict__ qa, u32 mA,
                                                  const u64* __restrict__ qb, u32 mB,
                                                  float* da, float* db, u32* panic){
  u64 a0=0,a1=0,b0=0,b1=0; bool oa0=false,oa1=false,ob0=false,ob1=false; u32 it=0;
  for(;;){
    if(!oa0) a0=__hip_atomic_load(qa,  __ATOMIC_RELAXED,__HIP_MEMORY_SCOPE_AGENT);
    if(!oa1) a1=__hip_atomic_load(qa+1,__ATOMIC_RELAXED,__HIP_MEMORY_SCOPE_AGENT);
    if(!ob0) b0=__hip_atomic_load(qb,  __ATOMIC_RELAXED,__HIP_MEMORY_SCOPE_AGENT);
    if(!ob1) b1=__hip_atomic_load(qb+1,__ATOMIC_RELAXED,__HIP_MEMORY_SCOPE_AGENT);
    oa0 = oa0 || tag_ok(a0,mA);
    oa1 = oa1 || tag_ok(a1,mA);
    ob0 = ob0 || tag_ok(b0,mB);
    ob1 = ob1 || tag_ok(b1,mB);
    if(oa0 & oa1 & ob0 & ob1) break;
    ++it;
    if((it & 255u)==0u){
      if(__hip_atomic_load(panic,__ATOMIC_RELAXED,__HIP_MEMORY_SCOPE_AGENT)==0xDEADBEEFu) break;
      if(it>PANIC_ITERS){ __hip_atomic_store(panic,0xDEADBEEFu,__ATOMIC_RELAXED,__HIP_MEMORY_SCOPE_AGENT); break; }
    }
    __builtin_amdgcn_s_sleep(1);
  }
  da[0]=untag1(a0); da[1]=untag1(a1);
  db[0]=untag1(b0); db[1]=untag1(b1);
}

// One LSTM layer over T steps. kb = block index within the layer (0..127).
// Block owns h-rows hr0..hr0+7; wave w owns row r=hr0+w entirely (4 gates).
// Lane l = one 32-col segment (lanes 0-31 input part, 32-63 h part).
// Thread stages stream elements 2*tid, 2*tid+1 of both IN and H parts.
// mode 0: input = raw x.  mode 1/3: input = tagged stream (m_in).
// mode 2: input = CONSTANT tagged slot (staged once; in-part persists).
static __device__ __forceinline__ void lstm_scan_body(
    int kb, int tid, float* st, float* gh,
    const float* __restrict__ xin,
    const u64*  __restrict__ instream,
    u64*        __restrict__ own,
    u32 m_in, u32 m_own,
    const float* __restrict__ Wih, const float* __restrict__ Whh,
    const float* __restrict__ bih, const float* __restrict__ bhh,
    const float* __restrict__ c0,      // null -> zeros
    float*       __restrict__ cout,    // final c per row
    const u64*  __restrict__ h0slot,   // tagged slot holding h0; null -> zeros
    float*       __restrict__ fh_out,  // if non-null: write final h (enc L1)
    u32* __restrict__ panic,
    int mode)
{
  const int hr0=kb*8;
  const int w=tid>>6, l=tid&63;
  const int r = hr0 + w;                   // this wave's h row
  const int e0 = 2*tid;                    // first owned stream element
  const int fb  = e0 + 4*(e0>>5);          // stage word, IN part (2 elems)
  const int fbH = 1152+fb;                 // stage word, H part
  const int sb  = l*36;                    // dot segment word base

  // fp32 weights in registers: 4 gate rows (i,f,g,o) x 32-col segment
  float wr0[32],wr1[32],wr2[32],wr3[32];
  {
    const size_t GS = (size_t)1024*1024;   // gate stride in floats
    const float* srcb = (l<32) ? Wih + (size_t)r*H_DIM + l*32
                               : Whh + (size_t)r*H_DIM + (l-32)*32;
    #pragma unroll
    for(int i=0;i<8;i++){
      float4 a0=*(const float4*)(srcb + i*4);
      float4 a1=*(const float4*)(srcb + GS + i*4);
      float4 a2=*(const float4*)(srcb + 2*GS + i*4);
      float4 a3=*(const float4*)(srcb + 3*GS + i*4);
      wr0[4*i]=a0.x; wr0[4*i+1]=a0.y; wr0[4*i+2]=a0.z; wr0[4*i+3]=a0.w;
      wr1[4*i]=a1.x; wr1[4*i+1]=a1.y; wr1[4*i+2]=a1.z; wr1[4*i+3]=a1.w;
      wr2[4*i]=a2.x; wr2[4*i+1]=a2.y; wr2[4*i+2]=a2.z; wr2[4*i+3]=a2.w;
      wr3[4*i]=a3.x; wr3[4*i+1]=a3.y; wr3[4*i+2]=a3.z; wr3[4*i+3]=a3.w;
    }
  }

  float bI=0,bF=0,bG=0,bO=0,c_st=0.f,h_st=0.f;   // valid on lane 0 of each wave
  if(l==0){
    bI=bih[r]       + bhh[r];
    bF=bih[r+1024]  + bhh[r+1024];
    bG=bih[r+2048]  + bhh[r+2048];
    bO=bih[r+3072]  + bhh[r+3072];
    if(c0)     c_st=c0[r];
    if(h0slot) h_st=untag1(h0slot[r]);
    gh[w]=h_st;
  }
  if(mode==2){                 // constant input: stage once (region persists)
    st[fb]  =untag1(instream[e0]);
    st[fb+1]=untag1(instream[e0+1]);
  }
  __syncthreads();
  // publish slot 0 (h0): 8 adjacent lanes of wave 0 -> one 64B transaction
  if(tid<8){
    __hip_atomic_store(own + hr0 + tid, tag1(m_own, gh[tid]),
                       __ATOMIC_RELAXED,__HIP_MEMORY_SCOPE_AGENT);
  }

  for(int t=0;t<T_STEPS;++t){
    // --- fill stage buffer (poll = single-hop tagged exchange) ---
    if(mode==0){
      float2 xv=*(const float2*)(xin + (size_t)t*H_DIM + e0);  // issue early
      poll_h2(own + (size_t)t*SLOT_U64 + e0, m_own, st+fbH, panic);
      st[fb]=xv.x; st[fb+1]=xv.y;                              // lands in poll
    } else if(mode==2){
      poll_h2(own + (size_t)t*SLOT_U64 + e0, m_own, st+fbH, panic);
    } else {
      poll_in2h2(instream + (size_t)(t+1)*SLOT_U64 + e0, m_in,
                 own      + (size_t)t*SLOT_U64     + e0, m_own,
                 st+fb, st+fbH, panic);
    }
    __syncthreads();
    // --- dot: 4 gates of row r over this lane's 32-col segment ---
    float p0=0.f,p1=0.f,p2=0.f,p3=0.f;
    #pragma unroll
    for(int i=0;i<8;i++){
      float4 s=*(const float4*)(st+sb+i*4);
      p0+=s.x*wr0[4*i]+s.y*wr0[4*i+1]+s.z*wr0[4*i+2]+s.w*wr0[4*i+3];
      p1+=s.x*wr1[4*i]+s.y*wr1[4*i+1]+s.z*wr1[4*i+2]+s.w*wr1[4*i+3];
      p2+=s.x*wr2[4*i]+s.y*wr2[4*i+1]+s.z*wr2[4*i+2]+s.w*wr2[4*i+3];
      p3+=s.x*wr3[4*i]+s.y*wr3[4*i+1]+s.z*wr3[4*i+2]+s.w*wr3[4*i+3];
    }
    #pragma unroll
    for(int off=32;off;off>>=1){
      p0+=__shfl_down(p0,off,64); p1+=__shfl_down(p1,off,64);
      p2+=__shfl_down(p2,off,64); p3+=__shfl_down(p3,off,64);
    }
    // --- gates fully in-wave (lane 0); h hops to wave 0 via gh[] ---
    if(l==0){
      float gi=bI+p0, gf=bF+p1, gg=bG+p2, go=bO+p3;
      c_st = sigf(gf)*c_st + sigf(gi)*tanh_f(gg);
      h_st = sigf(go)*tanh_f(c_st);
      gh[w]=h_st;
      if(t==T_STEPS-1){
        cout[r]=c_st;
        if(fh_out) fh_out[r]=h_st;
      }
    }
    __syncthreads();
    // --- coalesced publish: 8 adjacent lanes of wave 0, one 64B line.
    //     s_setprio(1) so the critical store wins memory-issue arbitration
    //     against the 7 waves that just started polling (round-10 lesson).
    if(w==0){
      __builtin_amdgcn_s_setprio(1);
      if(l<8){
        __hip_atomic_store(own + (size_t)(t+1)*SLOT_U64 + hr0 + l,
                           tag1(m_own, gh[l]),
                           __ATOMIC_RELAXED,__HIP_MEMORY_SCOPE_AGENT);
      }
      __builtin_amdgcn_s_setprio(0);
    }
    // single stage buffer is safe: all dot reads of st completed before
    // this barrier; next fill starts only after it.
  }
}

// Fused layer pair: blocks [0,128) = layer A, [128,256) = layer B.
// B consumes A's stream with 1-step skew. A never waits on B.
__global__ __launch_bounds__(512,2) void lstm_scan_pair(
    const float* __restrict__ xinA,
    const u64*  __restrict__ insA, u64* __restrict__ ownA, u32 miA, u32 moA,
    const float* __restrict__ WihA, const float* __restrict__ WhhA,
    const float* __restrict__ bihA, const float* __restrict__ bhhA,
    const float* __restrict__ c0A, float* __restrict__ coutA,
    const u64*  __restrict__ h0A, float* __restrict__ fhA, int modeA,
    const u64*  __restrict__ insB, u64* __restrict__ ownB, u32 miB, u32 moB,
    const float* __restrict__ WihB, const float* __restrict__ WhhB,
    const float* __restrict__ bihB, const float* __restrict__ bhhB,
    const float* __restrict__ c0B, float* __restrict__ coutB,
    const u64*  __restrict__ h0B, float* __restrict__ fhB, int modeB,
    u32* __restrict__ panic)
{
  __shared__ __align__(16) float st[2304];
  __shared__ float gh[8];
  const int b=blockIdx.x, tid=threadIdx.x;
  if(b<128){
    lstm_scan_body(b, tid, st, gh, xinA, insA, ownA, miA, moA,
                   WihA, WhhA, bihA, bhhA, c0A, coutA, h0A, fhA, panic, modeA);
  } else {
    lstm_scan_body(b-128, tid, st, gh, nullptr, insB, ownB, miB, moB,
                   WihB, WhhB, bihB, bhhB, c0B, coutB, h0B, fhB, panic, modeB);
  }
}

// out[(4095-tp), o] = leaky( sum_k oW[o,k] * h1d[tp][k] + ob[o] )
// Tiled: each block handles PTILE timesteps, staging h in LDS, so out_W is
// read 256x total (1 GB LLC traffic) instead of 4096x (16 GB).
#define PTILE 16
__global__ __launch_bounds__(256,2) void proj_out(
    const u64* __restrict__ SB, const float* __restrict__ oW,
    const float* __restrict__ ob, float* __restrict__ out)
{
  __shared__ __align__(16) float hb[PTILE][1024];
  const int tp0=blockIdx.x*PTILE, tid=threadIdx.x;
  for(int i=0;i<PTILE;i++){
    u64 v0=SB[(size_t)(tp0+i+1)*SLOT_U64 + tid*4 + 0];
    u64 v1=SB[(size_t)(tp0+i+1)*SLOT_U64 + tid*4 + 1];
    u64 v2=SB[(size_t)(tp0+i+1)*SLOT_U64 + tid*4 + 2];
    u64 v3=SB[(size_t)(tp0+i+1)*SLOT_U64 + tid*4 + 3];
    float4 f; f.x=untag1(v0); f.y=untag1(v1); f.z=untag1(v2); f.w=untag1(v3);
    *(float4*)&hb[i][tid*4]=f;
  }
  __syncthreads();
  #pragma unroll
  for(int j=0;j<4;j++){
    int o = tid + 256*j;
    const float* wr = oW + (size_t)o*H_DIM;
    float acc[PTILE];
    #pragma unroll
    for(int i=0;i<PTILE;i++) acc[i]=0.f;
    for(int k=0;k<1024;k+=4){
      float4 wv=*(const float4*)(wr+k);
      #pragma unroll
      for(int i=0;i<PTILE;i++){
        acc[i] += wv.x*hb[i][k]+wv.y*hb[i][k+1]+wv.z*hb[i][k+2]+wv.w*hb[i][k+3];
      }
    }
    float bo=ob[o];
    #pragma unroll
    for(int i=0;i<PTILE;i++){
      float a=acc[i]+bo;
      a = a>0.f ? a : 0.01f*a;
      out[(size_t)(4095-(tp0+i))*H_DIM + o]=a;
    }
  }
}

extern "C" void kernel_launch(void* const* d_in, const int* in_sizes, int n_in,
                              void* d_out, int out_size, void* d_ws, size_t ws_size,
                              hipStream_t stream) {
  const float* x    = (const float*)d_in[0];
  const float* eWih = (const float*)d_in[1];
  const float* eWhh = (const float*)d_in[2];
  const float* ebih = (const float*)d_in[3];
  const float* ebhh = (const float*)d_in[4];
  const float* dWih = (const float*)d_in[5];
  const float* dWhh = (const float*)d_in[6];
  const float* dbih = (const float*)d_in[7];
  const float* dbhh = (const float*)d_in[8];
  const float* oW   = (const float*)d_in[9];
  const float* ob   = (const float*)d_in[10];
  float* out = (float*)d_out;
  u32* ws = (u32*)d_ws;

  const size_t REGION = (size_t)NSLOT*SLOT_DW;     // in dwords
  u64*   SA    = (u64*)ws;
  u64*   SB    = (u64*)(ws + REGION);
  float* CA    = (float*)(ws + 2*REGION);          // 2048 floats: enc c finals
  u32*   panic = ws + 2*REGION + 2048;
  const size_t LSTRIDE = (size_t)4096*1024;        // per-layer weight stride

  // clear tags + c buffer + panic (stale same-magic tags from the previous
  // graph iteration must never false-positive)
  size_t clr_bytes = (2*REGION + 2048 + 64)*4;
  hipMemsetAsync(d_ws, 0, clr_bytes, stream);

  // Phase 1: enc L0 (mode 0, x -> SA/M1, zero init) || enc L1 (mode 1,
  // SA/M1 -> SB/M1, zero init, writes final_hidden to out tail).
  lstm_scan_pair<<<256,512,0,stream>>>(
      x, nullptr, SA, 0u, M1,
      eWih, eWhh, ebih, ebhh,
      nullptr, CA, nullptr, nullptr, 0,
      SA, SB, M1, M1,
      eWih+LSTRIDE, eWhh+LSTRIDE, ebih+4096, ebhh+4096,
      nullptr, CA+1024, nullptr, out + (size_t)T_STEPS*H_DIM, 1,
      panic);

  // Phase 2: dec L0 (mode 2, const input = final_hidden = SB slot 4096,
  // stream SA reused with M2, init h=SA slot 4096 / c=CA) || dec L1
  // (mode 3, SA/M2 -> SB/M2, init h=SB slot 4096 / c=CA+1024).
  lstm_scan_pair<<<256,512,0,stream>>>(
      nullptr, SB + (size_t)4096*SLOT_U64, SA, 0u, M2,
      dWih, dWhh, dbih, dbhh,
      CA, CA, SA + (size_t)4096*SLOT_U64, nullptr, 2,
      SA, SB, M2, M2,
      dWih+LSTRIDE, dWhh+LSTRIDE, dbih+4096, dbhh+4096,
      CA+1024, CA+1024, SB + (size_t)4096*SLOT_U64, nullptr, 3,
      panic);

  // projection + leaky ReLU + flip
  proj_out<<<256,256,0,stream>>>(SB, oW, ob, out);
}